// Round 3
// baseline (133.927 us; speedup 1.0000x reference)
//
#include <hip/hip_runtime.h>
#include <cstdint>

#define B_     4096
#define D_     256
#define KK_    6
#define T_     256
#define DEPTH_ 6
#define C_     8
#define F1     1536   // D*K
#define F2     3072   // 2*F1
#define NROW   1536   // T*DEPTH
#define KSEG   1536
#define KTOT   4608   // 3 segments: hi*hi, hi*lo, lo*hi
#define SPLITK 2
#define KSPL   2304   // KTOT / SPLITK
#define BK     64
#define NIT    (KSPL / BK)   // 36
#define NFB    24     // F1/64 blocks for prep_att

using bf16x8 = __attribute__((ext_vector_type(8))) __bf16;
using f32x4  = __attribute__((ext_vector_type(4))) float;

__device__ inline float waveSum(float v) {
#pragma unroll
  for (int m = 32; m; m >>= 1) v += __shfl_xor(v, m, 64);
  return v;
}
__device__ inline int waveSumI(int v) {
#pragma unroll
  for (int m = 32; m; m >>= 1) v += __shfl_xor(v, m, 64);
  return v;
}

__device__ __forceinline__ void gload_lds16(const void* g, void* l) {
  __builtin_amdgcn_global_load_lds(
      (const __attribute__((address_space(1))) unsigned int*)g,
      (__attribute__((address_space(3))) unsigned int*)l, 16, 0, 0);
}

// ---------------------------------------------------------------------------
// K0a: tile-transpose att_W -> watt hi/lo bf16 [T][F1]; partial catt col sums
// ---------------------------------------------------------------------------
__global__ __launch_bounds__(256) void prep_att_kernel(
    const float* __restrict__ att_W,
    __bf16* __restrict__ w_hi, __bf16* __restrict__ w_lo,
    float* __restrict__ pc)
{
  const int fblk = blockIdx.x * 64;   // over F1
  const int tblk = blockIdx.y * 64;   // over T
  __shared__ float Wl[64][65], Wh[64][65];
  const int tt = threadIdx.x & 63;
  const int f4 = threadIdx.x >> 6;
#pragma unroll
  for (int r = 0; r < 16; ++r) {
    const int f = r * 4 + f4;
    Wl[f][tt] = att_W[(size_t)(fblk + f) * T_ + tblk + tt];
    Wh[f][tt] = att_W[(size_t)(fblk + f + F1) * T_ + tblk + tt];
  }
  __syncthreads();
  const int t  = threadIdx.x >> 2;
  const int fq = threadIdx.x & 3;
#pragma unroll
  for (int pass = 0; pass < 4; ++pass) {
    const int f0 = pass * 16 + fq * 4;
    alignas(8) __bf16 hv[4];
    alignas(8) __bf16 lv[4];
#pragma unroll
    for (int e = 0; e < 4; ++e) {
      const float w = Wl[f0 + e][t] - Wh[f0 + e][t];
      const __bf16 h = (__bf16)w;
      hv[e] = h;
      lv[e] = (__bf16)(w - (float)h);
    }
    *(uint2*)&w_hi[(size_t)(tblk + t) * F1 + fblk + f0] = *(const uint2*)hv;
    *(uint2*)&w_lo[(size_t)(tblk + t) * F1 + fblk + f0] = *(const uint2*)lv;
  }
  if (threadIdx.x < 64) {
    float s = 0.f;
#pragma unroll
    for (int f = 0; f < 64; ++f) s += Wh[f][threadIdx.x];
    pc[(size_t)blockIdx.x * T_ + tblk + threadIdx.x] = s;
  }
}

__global__ __launch_bounds__(256) void catt_kernel(
    const float* __restrict__ pc, const float* __restrict__ att_b,
    float* __restrict__ catt)
{
  const int t = threadIdx.x;
  float s = att_b[t];
  for (int i = 0; i < NFB; ++i) s += pc[(size_t)i * T_ + t];
  catt[t] = s;
}

// ---------------------------------------------------------------------------
// K1: per-row sparsemax of sel_logits (Michelot), folded to packed sparse
// records {f32 val, u16 idx} + const c.  Rows zero-padded to multiple of 64.
// ---------------------------------------------------------------------------
__global__ __launch_bounds__(256) void sel_sparsemax_kernel(
    const float* __restrict__ sel_logits,
    uint2* __restrict__ w_pack,
    int* __restrict__ w_cnt, float* __restrict__ w_c)
{
  const int row = blockIdx.x;
  __shared__ float z[F2];
  __shared__ float rf[4];
  __shared__ int   ri[4];
  __shared__ float tau_sh;
  __shared__ int   cnt_sh;
  __shared__ int   scan_wave[4];
  __shared__ int   tot_sh;

  const float* src = sel_logits + (size_t)row * F2;
  for (int i = threadIdx.x; i < F2; i += 256) z[i] = src[i];
  __syncthreads();

  const int wid  = threadIdx.x >> 6;
  const int lane = threadIdx.x & 63;

  float tau = -1e30f;
  float tau_next = 0.f;
  int cprev = F2 + 1;
  for (int it = 0; it < 64; ++it) {
    float s = 0.f; int c = 0;
    for (int i = threadIdx.x; i < F2; i += 256) {
      const float zi = z[i];
      if (zi > tau) { s += zi; c++; }
    }
    s = waveSum(s); c = waveSumI(c);
    if (lane == 0) { rf[wid] = s; ri[wid] = c; }
    __syncthreads();
    if (threadIdx.x == 0) {
      const float st = rf[0] + rf[1] + rf[2] + rf[3];
      const int   ct = ri[0] + ri[1] + ri[2] + ri[3];
      tau_sh = (st - 1.0f) / (float)ct;
      cnt_sh = ct;
    }
    __syncthreads();
    tau_next = tau_sh;
    const int cn = cnt_sh;
    __syncthreads();
    if (cn == cprev) break;
    cprev = cn; tau = tau_next;
  }
  tau = tau_next;

  float chi = 0.f;
  float wv[6];
  int nnz = 0;
#pragma unroll
  for (int j = 0; j < 6; ++j) {
    const int fme = threadIdx.x + 256 * j;
    float lo = z[fme] - tau;       lo = lo > 0.f ? lo : 0.f;
    float hi = z[fme + F1] - tau;  hi = hi > 0.f ? hi : 0.f;
    chi += hi;
    wv[j] = lo - hi;
    if (wv[j] != 0.f) nnz++;
  }
  const float cs = waveSum(chi);
  if (lane == 0) rf[wid] = cs;

  int incl = nnz;
#pragma unroll
  for (int off = 1; off < 64; off <<= 1) {
    const int n = __shfl_up(incl, off, 64);
    if (lane >= off) incl += n;
  }
  if (lane == 63) scan_wave[wid] = incl;
  __syncthreads();
  if (threadIdx.x == 0) w_c[row] = rf[0] + rf[1] + rf[2] + rf[3];
  int wave_base = 0;
  for (int wp = 0; wp < wid; ++wp) wave_base += scan_wave[wp];
  int pos = wave_base + incl - nnz;
#pragma unroll
  for (int j = 0; j < 6; ++j) {
    if (wv[j] != 0.f) {
      w_pack[(size_t)row * F1 + pos] =
          make_uint2(__float_as_uint(wv[j]), (unsigned)(threadIdx.x + 256 * j));
      pos++;
    }
  }
  if (threadIdx.x == 255) { w_cnt[row] = pos; tot_sh = pos; }
  __syncthreads();
  const int tot  = tot_sh;
  const int nn64 = (tot + 63) & ~63;
  for (int i = tot + threadIdx.x; i < nn64; i += 256)
    w_pack[(size_t)row * F1 + i] = make_uint2(0u, 0u);
}

// ---------------------------------------------------------------------------
// K2: f = sigmoid((x-thr)*exp(log_beta)) -> bf16 hi/lo pair [B][F1]
// ---------------------------------------------------------------------------
__global__ __launch_bounds__(256) void f_kernel(
    const float* __restrict__ x, const float* __restrict__ thr,
    const float* __restrict__ log_beta,
    __bf16* __restrict__ f_hi, __bf16* __restrict__ f_lo)
{
  const int b = blockIdx.x;
  const int d = threadIdx.x;
  const float xv = x[(size_t)b * D_ + d];
#pragma unroll
  for (int k = 0; k < KK_; ++k) {
    const float beta = __expf(log_beta[d * KK_ + k]);
    const float tt = (xv - thr[d * KK_ + k]) * beta;
    const float s = 1.0f / (1.0f + __expf(-tt));
    const __bf16 h = (__bf16)s;
    f_hi[(size_t)b * F1 + d * KK_ + k] = h;
    f_lo[(size_t)b * F1 + d * KK_ + k] = (__bf16)(s - (float)h);
  }
}

// ---------------------------------------------------------------------------
// K3: MFMA GEMM, part[sp][b][t], K = 4608 = [f_hi*w_hi | f_hi*w_lo | f_lo*w_hi]
// ---------------------------------------------------------------------------
__global__ __launch_bounds__(256) void gemm_mfma_kernel(
    const __bf16* __restrict__ f_hi, const __bf16* __restrict__ f_lo,
    const __bf16* __restrict__ w_hi, const __bf16* __restrict__ w_lo,
    float* __restrict__ part)
{
  __shared__ __bf16 As[2][64 * 64];
  __shared__ __bf16 Bs[2][64 * 64];
  const int bm = blockIdx.x * 64;
  const int bn = blockIdx.y * 64;
  const int sp = blockIdx.z;
  const int tid = threadIdx.x;
  const int wid = tid >> 6, lane = tid & 63;
  const int wr = wid >> 1, wc = wid & 1;

  const int srow = lane >> 3;
  const int skb8 = ((lane & 7) ^ srow) << 3;

  const int l15   = lane & 15;
  const int mask  = (lane & 7) << 4;
  const int khalf = (lane >> 4) << 4;
  int offA[2][2], offB[2][2];
#pragma unroll
  for (int m = 0; m < 2; ++m) {
    const int row = wr * 32 + m * 16 + l15;
#pragma unroll
    for (int s = 0; s < 2; ++s)
      offA[m][s] = row * 128 + (((s << 6) | khalf) ^ mask);
  }
#pragma unroll
  for (int n = 0; n < 2; ++n) {
    const int col = wc * 32 + n * 16 + l15;
#pragma unroll
    for (int s = 0; s < 2; ++s)
      offB[n][s] = col * 128 + (((s << 6) | khalf) ^ mask);
  }

  f32x4 acc[2][2] = {};

  auto stage = [&](int it, int buf) {
    const int k0  = sp * KSPL + it * BK;
    const int seg = k0 / KSEG;
    const int kl  = k0 - seg * KSEG;
    const __bf16* __restrict__ asrc = (seg < 2) ? f_hi : f_lo;
    const __bf16* __restrict__ bsrc = (seg == 1) ? w_lo : w_hi;
#pragma unroll
    for (int j = 0; j < 2; ++j) {
      const int q = wid * 2 + j;
      gload_lds16(asrc + (size_t)(bm + q * 8 + srow) * F1 + kl + skb8, &As[buf][q * 512]);
      gload_lds16(bsrc + (size_t)(bn + q * 8 + srow) * F1 + kl + skb8, &Bs[buf][q * 512]);
    }
  };

  stage(0, 0);
  __syncthreads();
  for (int it = 0; it < NIT; ++it) {
    const int cur = it & 1;
    if (it + 1 < NIT) stage(it + 1, cur ^ 1);
    const char* pa = (const char*)As[cur];
    const char* pb = (const char*)Bs[cur];
#pragma unroll
    for (int s = 0; s < 2; ++s) {
      const bf16x8 a0 = *(const bf16x8*)(pa + offA[0][s]);
      const bf16x8 a1 = *(const bf16x8*)(pa + offA[1][s]);
      const bf16x8 b0 = *(const bf16x8*)(pb + offB[0][s]);
      const bf16x8 b1 = *(const bf16x8*)(pb + offB[1][s]);
      acc[0][0] = __builtin_amdgcn_mfma_f32_16x16x32_bf16(a0, b0, acc[0][0], 0, 0, 0);
      acc[0][1] = __builtin_amdgcn_mfma_f32_16x16x32_bf16(a0, b1, acc[0][1], 0, 0, 0);
      acc[1][0] = __builtin_amdgcn_mfma_f32_16x16x32_bf16(a1, b0, acc[1][0], 0, 0, 0);
      acc[1][1] = __builtin_amdgcn_mfma_f32_16x16x32_bf16(a1, b1, acc[1][1], 0, 0, 0);
    }
    __syncthreads();
  }

  const int r0 = (lane >> 4) << 2;
  float* outp = part + (size_t)sp * B_ * T_;
#pragma unroll
  for (int m = 0; m < 2; ++m)
#pragma unroll
    for (int n = 0; n < 2; ++n)
#pragma unroll
      for (int r = 0; r < 4; ++r)
        outp[(size_t)(bm + wr * 32 + m * 16 + r0 + r) * T_ + (bn + wc * 32 + n * 16 + l15)] =
            acc[m][n][r];
}

// ---------------------------------------------------------------------------
// K4: fused split-K reduce + catt + per-row sparsemax over T=256 + compaction
// ---------------------------------------------------------------------------
__global__ __launch_bounds__(64) void att_sparsemax_kernel(
    const float* __restrict__ part, const float* __restrict__ catt,
    unsigned short* __restrict__ a_idx, float* __restrict__ a_val,
    int* __restrict__ a_cnt)
{
  const int b = blockIdx.x;
  const int lane = threadIdx.x;
  float z[4];
#pragma unroll
  for (int j = 0; j < 4; ++j) {
    const int t = lane + 64 * j;
    z[j] = part[(size_t)b * T_ + t] + part[((size_t)B_ + b) * T_ + t] + catt[t];
  }
  float tau = -1e30f, taun = 0.f;
  int cprev = T_ + 1;
  for (int it = 0; it < 40; ++it) {
    float s = 0.f; int c = 0;
#pragma unroll
    for (int j = 0; j < 4; ++j) if (z[j] > tau) { s += z[j]; c++; }
    s = waveSum(s); c = waveSumI(c);
    taun = (s - 1.0f) / (float)c;
    if (c == cprev) break;
    cprev = c; tau = taun;
  }
  tau = taun;
  float av[4]; int nnz = 0;
#pragma unroll
  for (int j = 0; j < 4; ++j) {
    float a = z[j] - tau; av[j] = a > 0.f ? a : 0.f;
    if (av[j] > 0.f) nnz++;
  }
  int incl = nnz;
#pragma unroll
  for (int off = 1; off < 64; off <<= 1) {
    const int n = __shfl_up(incl, off, 64);
    if (lane >= off) incl += n;
  }
  int pos = incl - nnz;
#pragma unroll
  for (int j = 0; j < 4; ++j) {
    if (av[j] > 0.f) {
      a_idx[(size_t)b * T_ + pos] = (unsigned short)(lane + 64 * j);
      a_val[(size_t)b * T_ + pos] = av[j];
      pos++;
    }
  }
  if (lane == 63) a_cnt[b] = incl;
}

// ---------------------------------------------------------------------------
// K5: out[b,c] = sum over active t of a * sum_l prob_l * leaf[t,l,c]
// Interleaved 6-depth sparse dots (per-lane partials, one waveSum pass per t)
// ---------------------------------------------------------------------------
__global__ __launch_bounds__(256) void final_kernel(
    const __bf16* __restrict__ f_hi, const __bf16* __restrict__ f_lo,
    const uint2* __restrict__ w_pack,
    const int* __restrict__ w_cnt, const float* __restrict__ w_c,
    const unsigned short* __restrict__ a_idx, const float* __restrict__ a_val,
    const int* __restrict__ a_cnt,
    const float* __restrict__ leaf, float* __restrict__ out)
{
  const int b = blockIdx.x;
  __shared__ float fl[F1];
  __shared__ float oacc[4][C_];
  const int tid = threadIdx.x;
  const int wid = tid >> 6, lane = tid & 63;
  for (int i = tid; i < F1; i += 256)
    fl[i] = (float)f_hi[(size_t)b * F1 + i] + (float)f_lo[(size_t)b * F1 + i];
  __syncthreads();
  const int nact = a_cnt[b];
  float o[C_];
#pragma unroll
  for (int c = 0; c < C_; ++c) o[c] = 0.f;

  for (int i = wid; i < nact; i += 4) {
    const int t = a_idx[(size_t)b * T_ + i];
    const float aval = a_val[(size_t)b * T_ + i];
    const int row0 = t * DEPTH_;
    const uint2* wp = w_pack + (size_t)row0 * F1;

    int nk[DEPTH_]; int maxk = 0;
    float s[DEPTH_];
#pragma unroll
    for (int d = 0; d < DEPTH_; ++d) {
      s[d] = 0.f;
      nk[d] = (w_cnt[row0 + d] + 63) >> 6;
      maxk = nk[d] > maxk ? nk[d] : maxk;
    }
    for (int k = 0; k < maxk; ++k) {
#pragma unroll
      for (int d = 0; d < DEPTH_; ++d) {
        if (k < nk[d]) {
          const uint2 u = wp[(size_t)d * F1 + k * 64 + lane];
          s[d] += __uint_as_float(u.x) * fl[u.y];
        }
      }
    }
    float p[DEPTH_];
#pragma unroll
    for (int d = 0; d < DEPTH_; ++d) {
      float pv = w_c[row0 + d] + waveSum(s[d]);
      p[d] = pv < 1e-6f ? 1e-6f : (pv > 1.0f - 1e-6f ? 1.0f - 1e-6f : pv);
    }
    float prob = aval;
#pragma unroll
    for (int d = 0; d < DEPTH_; ++d) prob *= ((lane >> d) & 1) ? p[d] : (1.0f - p[d]);
    const float* lf = leaf + ((size_t)t * 64 + lane) * C_;
#pragma unroll
    for (int c = 0; c < C_; ++c) o[c] += prob * lf[c];
  }
#pragma unroll
  for (int c = 0; c < C_; ++c) o[c] = waveSum(o[c]);
  if (lane == 0) {
#pragma unroll
    for (int c = 0; c < C_; ++c) oacc[wid][c] = o[c];
  }
  __syncthreads();
  if (tid < C_)
    out[(size_t)b * C_ + tid] = oacc[0][tid] + oacc[1][tid] + oacc[2][tid] + oacc[3][tid];
}

// ---------------------------------------------------------------------------
extern "C" void kernel_launch(void* const* d_in, const int* in_sizes, int n_in,
                              void* d_out, int out_size, void* d_ws, size_t ws_size,
                              hipStream_t stream)
{
  const float* x        = (const float*)d_in[0];
  const float* thr      = (const float*)d_in[1];
  const float* log_beta = (const float*)d_in[2];
  const float* sel      = (const float*)d_in[3];
  const float* leaf     = (const float*)d_in[4];
  const float* att_W    = (const float*)d_in[5];
  const float* att_b    = (const float*)d_in[6];
  float* out = (float*)d_out;

  char* ws = (char*)d_ws;
  size_t off = 0;
  auto alloc = [&](size_t bytes) {
    char* p = ws + off;
    off = (off + bytes + 255) & ~(size_t)255;
    return p;
  };
  __bf16*         f_hi   = (__bf16*)alloc((size_t)B_ * F1 * 2);          // 12.6 MB
  __bf16*         f_lo   = (__bf16*)alloc((size_t)B_ * F1 * 2);          // 12.6 MB
  __bf16*         w_hi   = (__bf16*)alloc((size_t)T_ * F1 * 2);          //  0.8 MB
  __bf16*         w_lo   = (__bf16*)alloc((size_t)T_ * F1 * 2);          //  0.8 MB
  float*          catt   = (float*)alloc((size_t)T_ * 4);
  float*          pc     = (float*)alloc((size_t)NFB * T_ * 4);
  uint2*          w_pack = (uint2*)alloc((size_t)NROW * F1 * 8);         // 18.9 MB
  int*            w_cnt  = (int*)alloc((size_t)NROW * 4);
  float*          w_c    = (float*)alloc((size_t)NROW * 4);
  float*          part   = (float*)alloc((size_t)SPLITK * B_ * T_ * 4);  //  8.4 MB
  unsigned short* a_idx  = (unsigned short*)alloc((size_t)B_ * T_ * 2);  //  2.1 MB
  float*          a_val  = (float*)alloc((size_t)B_ * T_ * 4);           //  4.2 MB
  int*            a_cnt  = (int*)alloc((size_t)B_ * 4);
  (void)ws_size; (void)in_sizes; (void)n_in; (void)out_size;             // ~61 MB total

  hipLaunchKernelGGL(prep_att_kernel,      dim3(NFB, T_ / 64),        dim3(256), 0, stream, att_W, w_hi, w_lo, pc);
  hipLaunchKernelGGL(catt_kernel,          dim3(1),                   dim3(256), 0, stream, pc, att_b, catt);
  hipLaunchKernelGGL(sel_sparsemax_kernel, dim3(NROW),                dim3(256), 0, stream, sel, w_pack, w_cnt, w_c);
  hipLaunchKernelGGL(f_kernel,             dim3(B_),                  dim3(256), 0, stream, x, thr, log_beta, f_hi, f_lo);
  hipLaunchKernelGGL(gemm_mfma_kernel,     dim3(B_ / 64, T_ / 64, SPLITK), dim3(256), 0, stream, f_hi, f_lo, w_hi, w_lo, part);
  hipLaunchKernelGGL(att_sparsemax_kernel, dim3(B_),                  dim3(64),  0, stream, part, catt, a_idx, a_val, a_cnt);
  hipLaunchKernelGGL(final_kernel,         dim3(B_),                  dim3(256), 0, stream, f_hi, f_lo, w_pack, w_cnt, w_c, a_idx, a_val, a_cnt, leaf, out);
}

// Round 4
// 123.306 us; speedup vs baseline: 1.0861x; 1.0861x over previous
//
#include <hip/hip_runtime.h>
#include <cstdint>

#define B_     4096
#define D_     256
#define KK_    6
#define T_     256
#define DEPTH_ 6
#define C_     8
#define F1     1536   // D*K
#define F2     3072   // 2*F1
#define NROW   1536   // T*DEPTH
#define KSEG   1536
#define KTOT   4608   // 3 segments: hi*hi, hi*lo, lo*hi
#define SPLITK 2
#define KSPL   2304   // KTOT / SPLITK
#define BK     64
#define NIT    (KSPL / BK)   // 36
#define NFB    24     // F1/64 blocks for prep_att

using bf16x8 = __attribute__((ext_vector_type(8))) __bf16;
using f32x4  = __attribute__((ext_vector_type(4))) float;

__device__ inline float waveSum(float v) {
#pragma unroll
  for (int m = 32; m; m >>= 1) v += __shfl_xor(v, m, 64);
  return v;
}
__device__ inline int waveSumI(int v) {
#pragma unroll
  for (int m = 32; m; m >>= 1) v += __shfl_xor(v, m, 64);
  return v;
}

__device__ __forceinline__ void gload_lds16(const void* g, void* l) {
  __builtin_amdgcn_global_load_lds(
      (const __attribute__((address_space(1))) unsigned int*)g,
      (__attribute__((address_space(3))) unsigned int*)l, 16, 0, 0);
}

// ---------------------------------------------------------------------------
// K0a: tile-transpose att_W -> watt hi/lo bf16 [T][F1]; partial catt col sums
// ---------------------------------------------------------------------------
__global__ __launch_bounds__(256) void prep_att_kernel(
    const float* __restrict__ att_W,
    __bf16* __restrict__ w_hi, __bf16* __restrict__ w_lo,
    float* __restrict__ pc)
{
  const int fblk = blockIdx.x * 64;   // over F1
  const int tblk = blockIdx.y * 64;   // over T
  __shared__ float Wl[64][65], Wh[64][65];
  const int tt = threadIdx.x & 63;
  const int f4 = threadIdx.x >> 6;
#pragma unroll
  for (int r = 0; r < 16; ++r) {
    const int f = r * 4 + f4;
    Wl[f][tt] = att_W[(size_t)(fblk + f) * T_ + tblk + tt];
    Wh[f][tt] = att_W[(size_t)(fblk + f + F1) * T_ + tblk + tt];
  }
  __syncthreads();
  const int t  = threadIdx.x >> 2;
  const int fq = threadIdx.x & 3;
#pragma unroll
  for (int pass = 0; pass < 4; ++pass) {
    const int f0 = pass * 16 + fq * 4;
    alignas(8) __bf16 hv[4];
    alignas(8) __bf16 lv[4];
#pragma unroll
    for (int e = 0; e < 4; ++e) {
      const float w = Wl[f0 + e][t] - Wh[f0 + e][t];
      const __bf16 h = (__bf16)w;
      hv[e] = h;
      lv[e] = (__bf16)(w - (float)h);
    }
    *(uint2*)&w_hi[(size_t)(tblk + t) * F1 + fblk + f0] = *(const uint2*)hv;
    *(uint2*)&w_lo[(size_t)(tblk + t) * F1 + fblk + f0] = *(const uint2*)lv;
  }
  if (threadIdx.x < 64) {
    float s = 0.f;
#pragma unroll
    for (int f = 0; f < 64; ++f) s += Wh[f][threadIdx.x];
    pc[(size_t)blockIdx.x * T_ + tblk + threadIdx.x] = s;
  }
}

__global__ __launch_bounds__(256) void catt_kernel(
    const float* __restrict__ pc, const float* __restrict__ att_b,
    float* __restrict__ catt)
{
  const int t = threadIdx.x;
  float s = att_b[t];
  for (int i = 0; i < NFB; ++i) s += pc[(size_t)i * T_ + t];
  catt[t] = s;
}

// ---------------------------------------------------------------------------
// K1: per-row sparsemax of sel_logits (Michelot), folded to packed sparse
// records {f32 val, u32 idx} + const c.  Rows zero-padded to multiple of 256
// records so consumers can read 4 chunks of 64 unconditionally.
// ---------------------------------------------------------------------------
__global__ __launch_bounds__(256) void sel_sparsemax_kernel(
    const float* __restrict__ sel_logits,
    uint2* __restrict__ w_pack,
    int* __restrict__ w_cnt, float* __restrict__ w_c)
{
  const int row = blockIdx.x;
  __shared__ float z[F2];
  __shared__ float rf[4];
  __shared__ int   ri[4];
  __shared__ float tau_sh;
  __shared__ int   cnt_sh;
  __shared__ int   scan_wave[4];
  __shared__ int   tot_sh;

  const float* src = sel_logits + (size_t)row * F2;
  for (int i = threadIdx.x; i < F2; i += 256) z[i] = src[i];
  __syncthreads();

  const int wid  = threadIdx.x >> 6;
  const int lane = threadIdx.x & 63;

  float tau = -1e30f;
  float tau_next = 0.f;
  int cprev = F2 + 1;
  for (int it = 0; it < 64; ++it) {
    float s = 0.f; int c = 0;
    for (int i = threadIdx.x; i < F2; i += 256) {
      const float zi = z[i];
      if (zi > tau) { s += zi; c++; }
    }
    s = waveSum(s); c = waveSumI(c);
    if (lane == 0) { rf[wid] = s; ri[wid] = c; }
    __syncthreads();
    if (threadIdx.x == 0) {
      const float st = rf[0] + rf[1] + rf[2] + rf[3];
      const int   ct = ri[0] + ri[1] + ri[2] + ri[3];
      tau_sh = (st - 1.0f) / (float)ct;
      cnt_sh = ct;
    }
    __syncthreads();
    tau_next = tau_sh;
    const int cn = cnt_sh;
    __syncthreads();
    if (cn == cprev) break;
    cprev = cn; tau = tau_next;
  }
  tau = tau_next;

  float chi = 0.f;
  float wv[6];
  int nnz = 0;
#pragma unroll
  for (int j = 0; j < 6; ++j) {
    const int fme = threadIdx.x + 256 * j;
    float lo = z[fme] - tau;       lo = lo > 0.f ? lo : 0.f;
    float hi = z[fme + F1] - tau;  hi = hi > 0.f ? hi : 0.f;
    chi += hi;
    wv[j] = lo - hi;
    if (wv[j] != 0.f) nnz++;
  }
  const float cs = waveSum(chi);
  if (lane == 0) rf[wid] = cs;

  int incl = nnz;
#pragma unroll
  for (int off = 1; off < 64; off <<= 1) {
    const int n = __shfl_up(incl, off, 64);
    if (lane >= off) incl += n;
  }
  if (lane == 63) scan_wave[wid] = incl;
  __syncthreads();
  if (threadIdx.x == 0) w_c[row] = rf[0] + rf[1] + rf[2] + rf[3];
  int wave_base = 0;
  for (int wp = 0; wp < wid; ++wp) wave_base += scan_wave[wp];
  int pos = wave_base + incl - nnz;
#pragma unroll
  for (int j = 0; j < 6; ++j) {
    if (wv[j] != 0.f) {
      w_pack[(size_t)row * F1 + pos] =
          make_uint2(__float_as_uint(wv[j]), (unsigned)(threadIdx.x + 256 * j));
      pos++;
    }
  }
  if (threadIdx.x == 255) { w_cnt[row] = pos; tot_sh = pos; }
  __syncthreads();
  const int tot  = tot_sh;
  int npad = (tot + 255) & ~255;          // pad to multiple of 256 records
  if (npad > F1) npad = F1;
  for (int i = tot + threadIdx.x; i < npad; i += 256)
    w_pack[(size_t)row * F1 + i] = make_uint2(0u, 0u);
}

// ---------------------------------------------------------------------------
// K2: f = sigmoid((x-thr)*exp(log_beta)) -> bf16 hi/lo pair [B][F1]
// ---------------------------------------------------------------------------
__global__ __launch_bounds__(256) void f_kernel(
    const float* __restrict__ x, const float* __restrict__ thr,
    const float* __restrict__ log_beta,
    __bf16* __restrict__ f_hi, __bf16* __restrict__ f_lo)
{
  const int b = blockIdx.x;
  const int d = threadIdx.x;
  const float xv = x[(size_t)b * D_ + d];
#pragma unroll
  for (int k = 0; k < KK_; ++k) {
    const float beta = __expf(log_beta[d * KK_ + k]);
    const float tt = (xv - thr[d * KK_ + k]) * beta;
    const float s = 1.0f / (1.0f + __expf(-tt));
    const __bf16 h = (__bf16)s;
    f_hi[(size_t)b * F1 + d * KK_ + k] = h;
    f_lo[(size_t)b * F1 + d * KK_ + k] = (__bf16)(s - (float)h);
  }
}

// ---------------------------------------------------------------------------
// K3: MFMA GEMM, part[sp][b][t], K = 4608 = [f_hi*w_hi | f_hi*w_lo | f_lo*w_hi]
// ---------------------------------------------------------------------------
__global__ __launch_bounds__(256) void gemm_mfma_kernel(
    const __bf16* __restrict__ f_hi, const __bf16* __restrict__ f_lo,
    const __bf16* __restrict__ w_hi, const __bf16* __restrict__ w_lo,
    float* __restrict__ part)
{
  __shared__ __bf16 As[2][64 * 64];
  __shared__ __bf16 Bs[2][64 * 64];
  const int bm = blockIdx.x * 64;
  const int bn = blockIdx.y * 64;
  const int sp = blockIdx.z;
  const int tid = threadIdx.x;
  const int wid = tid >> 6, lane = tid & 63;
  const int wr = wid >> 1, wc = wid & 1;

  const int srow = lane >> 3;
  const int skb8 = ((lane & 7) ^ srow) << 3;

  const int l15   = lane & 15;
  const int mask  = (lane & 7) << 4;
  const int khalf = (lane >> 4) << 4;
  int offA[2][2], offB[2][2];
#pragma unroll
  for (int m = 0; m < 2; ++m) {
    const int row = wr * 32 + m * 16 + l15;
#pragma unroll
    for (int s = 0; s < 2; ++s)
      offA[m][s] = row * 128 + (((s << 6) | khalf) ^ mask);
  }
#pragma unroll
  for (int n = 0; n < 2; ++n) {
    const int col = wc * 32 + n * 16 + l15;
#pragma unroll
    for (int s = 0; s < 2; ++s)
      offB[n][s] = col * 128 + (((s << 6) | khalf) ^ mask);
  }

  f32x4 acc[2][2] = {};

  auto stage = [&](int it, int buf) {
    const int k0  = sp * KSPL + it * BK;
    const int seg = k0 / KSEG;
    const int kl  = k0 - seg * KSEG;
    const __bf16* __restrict__ asrc = (seg < 2) ? f_hi : f_lo;
    const __bf16* __restrict__ bsrc = (seg == 1) ? w_lo : w_hi;
#pragma unroll
    for (int j = 0; j < 2; ++j) {
      const int q = wid * 2 + j;
      gload_lds16(asrc + (size_t)(bm + q * 8 + srow) * F1 + kl + skb8, &As[buf][q * 512]);
      gload_lds16(bsrc + (size_t)(bn + q * 8 + srow) * F1 + kl + skb8, &Bs[buf][q * 512]);
    }
  };

  stage(0, 0);
  __syncthreads();
  for (int it = 0; it < NIT; ++it) {
    const int cur = it & 1;
    if (it + 1 < NIT) stage(it + 1, cur ^ 1);
    const char* pa = (const char*)As[cur];
    const char* pb = (const char*)Bs[cur];
#pragma unroll
    for (int s = 0; s < 2; ++s) {
      const bf16x8 a0 = *(const bf16x8*)(pa + offA[0][s]);
      const bf16x8 a1 = *(const bf16x8*)(pa + offA[1][s]);
      const bf16x8 b0 = *(const bf16x8*)(pb + offB[0][s]);
      const bf16x8 b1 = *(const bf16x8*)(pb + offB[1][s]);
      acc[0][0] = __builtin_amdgcn_mfma_f32_16x16x32_bf16(a0, b0, acc[0][0], 0, 0, 0);
      acc[0][1] = __builtin_amdgcn_mfma_f32_16x16x32_bf16(a0, b1, acc[0][1], 0, 0, 0);
      acc[1][0] = __builtin_amdgcn_mfma_f32_16x16x32_bf16(a1, b0, acc[1][0], 0, 0, 0);
      acc[1][1] = __builtin_amdgcn_mfma_f32_16x16x32_bf16(a1, b1, acc[1][1], 0, 0, 0);
    }
    __syncthreads();
  }

  const int r0 = (lane >> 4) << 2;
  float* outp = part + (size_t)sp * B_ * T_;
#pragma unroll
  for (int m = 0; m < 2; ++m)
#pragma unroll
    for (int n = 0; n < 2; ++n)
#pragma unroll
      for (int r = 0; r < 4; ++r)
        outp[(size_t)(bm + wr * 32 + m * 16 + r0 + r) * T_ + (bn + wc * 32 + n * 16 + l15)] =
            acc[m][n][r];
}

// ---------------------------------------------------------------------------
// K4: fused split-K reduce + catt + per-row sparsemax over T=256 + compaction
// packed output: a_pack[b*T+i] = {bits(a_val), t}
// ---------------------------------------------------------------------------
__global__ __launch_bounds__(64) void att_sparsemax_kernel(
    const float* __restrict__ part, const float* __restrict__ catt,
    uint2* __restrict__ a_pack, int* __restrict__ a_cnt)
{
  const int b = blockIdx.x;
  const int lane = threadIdx.x;
  float z[4];
#pragma unroll
  for (int j = 0; j < 4; ++j) {
    const int t = lane + 64 * j;
    z[j] = part[(size_t)b * T_ + t] + part[((size_t)B_ + b) * T_ + t] + catt[t];
  }
  float tau = -1e30f, taun = 0.f;
  int cprev = T_ + 1;
  for (int it = 0; it < 40; ++it) {
    float s = 0.f; int c = 0;
#pragma unroll
    for (int j = 0; j < 4; ++j) if (z[j] > tau) { s += z[j]; c++; }
    s = waveSum(s); c = waveSumI(c);
    taun = (s - 1.0f) / (float)c;
    if (c == cprev) break;
    cprev = c; tau = taun;
  }
  tau = taun;
  float av[4]; int nnz = 0;
#pragma unroll
  for (int j = 0; j < 4; ++j) {
    float a = z[j] - tau; av[j] = a > 0.f ? a : 0.f;
    if (av[j] > 0.f) nnz++;
  }
  int incl = nnz;
#pragma unroll
  for (int off = 1; off < 64; off <<= 1) {
    const int n = __shfl_up(incl, off, 64);
    if (lane >= off) incl += n;
  }
  int pos = incl - nnz;
#pragma unroll
  for (int j = 0; j < 4; ++j) {
    if (av[j] > 0.f) {
      a_pack[(size_t)b * T_ + pos] =
          make_uint2(__float_as_uint(av[j]), (unsigned)(lane + 64 * j));
      pos++;
    }
  }
  if (lane == 63) a_cnt[b] = incl;
}

// ---------------------------------------------------------------------------
// K5: out[b,c] = sum over active t of a * sum_l prob_l * leaf[t,l,c]
// Phase 1: task-flattened (active-idx, depth) sparse dots -> p_sh[i][d]
// Phase 2: per active t, lane=leaf, product + leaf dot
// ---------------------------------------------------------------------------
__global__ __launch_bounds__(256) void final_kernel(
    const __bf16* __restrict__ f_hi, const __bf16* __restrict__ f_lo,
    const uint2* __restrict__ w_pack,
    const int* __restrict__ w_cnt, const float* __restrict__ w_c,
    const uint2* __restrict__ a_pack, const int* __restrict__ a_cnt,
    const float* __restrict__ leaf, float* __restrict__ out)
{
  const int b = blockIdx.x;
  __shared__ float fl[F1];
  __shared__ float p_sh[T_][DEPTH_];
  __shared__ float oacc[4][C_];
  const int tid = threadIdx.x;
  const int wid = tid >> 6, lane = tid & 63;
  for (int i = tid; i < F1; i += 256)
    fl[i] = (float)f_hi[(size_t)b * F1 + i] + (float)f_lo[(size_t)b * F1 + i];
  __syncthreads();
  const int nact = a_cnt[b];
  const int ntask = nact * DEPTH_;

  // Phase 1: each wave takes tasks j = i*6+d round-robin
  for (int j = wid; j < ntask; j += 4) {
    const int i = j / 6;
    const int d = j - i * 6;
    const unsigned t = a_pack[(size_t)b * T_ + i].y;
    const int row = (int)t * DEPTH_ + d;
    const float wc = w_c[row];
    const int nk = (w_cnt[row] + 63) >> 6;
    const uint2* wp = w_pack + (unsigned)(row * F1) + lane;
    // first 4 chunks unconditional (rows are zero-padded to 256 records)
    const uint2 u0 = wp[0];
    const uint2 u1 = wp[64];
    const uint2 u2 = wp[128];
    const uint2 u3 = wp[192];
    float s = __uint_as_float(u0.x) * fl[u0.y];
    s += __uint_as_float(u1.x) * fl[u1.y];
    s += __uint_as_float(u2.x) * fl[u2.y];
    s += __uint_as_float(u3.x) * fl[u3.y];
    for (int k = 4; k < nk; ++k) {
      const uint2 u = wp[k * 64];
      s += __uint_as_float(u.x) * fl[u.y];
    }
    s = waveSum(s);
    if (lane == 0) {
      const float pv = wc + s;
      p_sh[i][d] = pv < 1e-6f ? 1e-6f : (pv > 1.0f - 1e-6f ? 1.0f - 1e-6f : pv);
    }
  }
  __syncthreads();

  // Phase 2: lane = leaf index
  float o[C_];
#pragma unroll
  for (int c = 0; c < C_; ++c) o[c] = 0.f;
  for (int i = wid; i < nact; i += 4) {
    const uint2 ap = a_pack[(size_t)b * T_ + i];
    float prob = __uint_as_float(ap.x);
#pragma unroll
    for (int d = 0; d < DEPTH_; ++d) {
      const float pv = p_sh[i][d];
      prob *= ((lane >> d) & 1) ? pv : (1.0f - pv);
    }
    const float* lf = leaf + ((size_t)ap.y * 64 + lane) * C_;
#pragma unroll
    for (int c = 0; c < C_; ++c) o[c] += prob * lf[c];
  }
#pragma unroll
  for (int c = 0; c < C_; ++c) o[c] = waveSum(o[c]);
  if (lane == 0) {
#pragma unroll
    for (int c = 0; c < C_; ++c) oacc[wid][c] = o[c];
  }
  __syncthreads();
  if (tid < C_)
    out[(size_t)b * C_ + tid] = oacc[0][tid] + oacc[1][tid] + oacc[2][tid] + oacc[3][tid];
}

// ---------------------------------------------------------------------------
extern "C" void kernel_launch(void* const* d_in, const int* in_sizes, int n_in,
                              void* d_out, int out_size, void* d_ws, size_t ws_size,
                              hipStream_t stream)
{
  const float* x        = (const float*)d_in[0];
  const float* thr      = (const float*)d_in[1];
  const float* log_beta = (const float*)d_in[2];
  const float* sel      = (const float*)d_in[3];
  const float* leaf     = (const float*)d_in[4];
  const float* att_W    = (const float*)d_in[5];
  const float* att_b    = (const float*)d_in[6];
  float* out = (float*)d_out;

  char* ws = (char*)d_ws;
  size_t off = 0;
  auto alloc = [&](size_t bytes) {
    char* p = ws + off;
    off = (off + bytes + 255) & ~(size_t)255;
    return p;
  };
  __bf16*         f_hi   = (__bf16*)alloc((size_t)B_ * F1 * 2);          // 12.6 MB
  __bf16*         f_lo   = (__bf16*)alloc((size_t)B_ * F1 * 2);          // 12.6 MB
  __bf16*         w_hi   = (__bf16*)alloc((size_t)T_ * F1 * 2);          //  0.8 MB
  __bf16*         w_lo   = (__bf16*)alloc((size_t)T_ * F1 * 2);          //  0.8 MB
  float*          catt   = (float*)alloc((size_t)T_ * 4);
  float*          pc     = (float*)alloc((size_t)NFB * T_ * 4);
  uint2*          w_pack = (uint2*)alloc((size_t)NROW * F1 * 8);         // 18.9 MB
  int*            w_cnt  = (int*)alloc((size_t)NROW * 4);
  float*          w_c    = (float*)alloc((size_t)NROW * 4);
  float*          part   = (float*)alloc((size_t)SPLITK * B_ * T_ * 4);  //  8.4 MB
  uint2*          a_pack = (uint2*)alloc((size_t)B_ * T_ * 8);           //  8.4 MB
  int*            a_cnt  = (int*)alloc((size_t)B_ * 4);
  (void)ws_size; (void)in_sizes; (void)n_in; (void)out_size;             // ~62 MB total

  hipLaunchKernelGGL(prep_att_kernel,      dim3(NFB, T_ / 64),        dim3(256), 0, stream, att_W, w_hi, w_lo, pc);
  hipLaunchKernelGGL(catt_kernel,          dim3(1),                   dim3(256), 0, stream, pc, att_b, catt);
  hipLaunchKernelGGL(sel_sparsemax_kernel, dim3(NROW),                dim3(256), 0, stream, sel, w_pack, w_cnt, w_c);
  hipLaunchKernelGGL(f_kernel,             dim3(B_),                  dim3(256), 0, stream, x, thr, log_beta, f_hi, f_lo);
  hipLaunchKernelGGL(gemm_mfma_kernel,     dim3(B_ / 64, T_ / 64, SPLITK), dim3(256), 0, stream, f_hi, f_lo, w_hi, w_lo, part);
  hipLaunchKernelGGL(att_sparsemax_kernel, dim3(B_),                  dim3(64),  0, stream, part, catt, a_pack, a_cnt);
  hipLaunchKernelGGL(final_kernel,         dim3(B_),                  dim3(256), 0, stream, f_hi, f_lo, w_pack, w_cnt, w_c, a_pack, a_cnt, leaf, out);
}

// Round 5
// 104.070 us; speedup vs baseline: 1.2869x; 1.1848x over previous
//
#include <hip/hip_runtime.h>
#include <cstdint>

#define B_     4096
#define D_     256
#define KK_    6
#define T_     256
#define DEPTH_ 6
#define C_     8
#define F1     1536   // D*K
#define F2     3072   // 2*F1
#define NROW   1536   // T*DEPTH
#define KSEG   1536
#define KTOT   4608   // 3 segments: hi*hi, hi*lo, lo*hi
#define SPLITK 4
#define KSPL   1152   // KTOT / SPLITK
#define BK     64
#define NIT    (KSPL / BK)   // 18
#define NFB    24     // F1/64 blocks for prep_att

using bf16x8 = __attribute__((ext_vector_type(8))) __bf16;
using f32x4  = __attribute__((ext_vector_type(4))) float;

__device__ inline float waveSum(float v) {
#pragma unroll
  for (int m = 32; m; m >>= 1) v += __shfl_xor(v, m, 64);
  return v;
}
__device__ inline int waveSumI(int v) {
#pragma unroll
  for (int m = 32; m; m >>= 1) v += __shfl_xor(v, m, 64);
  return v;
}

__device__ inline unsigned short bf16_bits(float v) {   // round-to-nearest-even
  const unsigned u = __float_as_uint(v);
  return (unsigned short)((u + 0x7FFFu + ((u >> 16) & 1u)) >> 16);
}
__device__ inline float bf16_val(unsigned rec) {        // low 16 bits -> f32
  return __uint_as_float(rec << 16);
}

__device__ __forceinline__ void gload_lds16(const void* g, void* l) {
  __builtin_amdgcn_global_load_lds(
      (const __attribute__((address_space(1))) unsigned int*)g,
      (__attribute__((address_space(3))) unsigned int*)l, 16, 0, 0);
}

// ---------------------------------------------------------------------------
// K0a: tile-transpose att_W -> watt hi/lo bf16 [T][F1]; partial catt col sums
// ---------------------------------------------------------------------------
__global__ __launch_bounds__(256) void prep_att_kernel(
    const float* __restrict__ att_W,
    __bf16* __restrict__ w_hi, __bf16* __restrict__ w_lo,
    float* __restrict__ pc)
{
  const int fblk = blockIdx.x * 64;   // over F1
  const int tblk = blockIdx.y * 64;   // over T
  __shared__ float Wl[64][65], Wh[64][65];
  const int tt = threadIdx.x & 63;
  const int f4 = threadIdx.x >> 6;
#pragma unroll
  for (int r = 0; r < 16; ++r) {
    const int f = r * 4 + f4;
    Wl[f][tt] = att_W[(size_t)(fblk + f) * T_ + tblk + tt];
    Wh[f][tt] = att_W[(size_t)(fblk + f + F1) * T_ + tblk + tt];
  }
  __syncthreads();
  const int t  = threadIdx.x >> 2;
  const int fq = threadIdx.x & 3;
#pragma unroll
  for (int pass = 0; pass < 4; ++pass) {
    const int f0 = pass * 16 + fq * 4;
    alignas(8) __bf16 hv[4];
    alignas(8) __bf16 lv[4];
#pragma unroll
    for (int e = 0; e < 4; ++e) {
      const float w = Wl[f0 + e][t] - Wh[f0 + e][t];
      const __bf16 h = (__bf16)w;
      hv[e] = h;
      lv[e] = (__bf16)(w - (float)h);
    }
    *(uint2*)&w_hi[(size_t)(tblk + t) * F1 + fblk + f0] = *(const uint2*)hv;
    *(uint2*)&w_lo[(size_t)(tblk + t) * F1 + fblk + f0] = *(const uint2*)lv;
  }
  if (threadIdx.x < 64) {
    float s = 0.f;
#pragma unroll
    for (int f = 0; f < 64; ++f) s += Wh[f][threadIdx.x];
    pc[(size_t)blockIdx.x * T_ + tblk + threadIdx.x] = s;
  }
}

__global__ __launch_bounds__(256) void catt_kernel(
    const float* __restrict__ pc, const float* __restrict__ att_b,
    float* __restrict__ catt)
{
  const int t = threadIdx.x;
  float s = att_b[t];
  for (int i = 0; i < NFB; ++i) s += pc[(size_t)i * T_ + t];
  catt[t] = s;
}

// ---------------------------------------------------------------------------
// K1: per-row sparsemax of sel_logits, 1 wave per row, all-register Michelot.
// Output: packed records {u16 idx | bf16 val} + const c; rows zero-padded to
// a multiple of 256 records.
// Lane layout: z[q][r] = row[256*q + 4*lane + r], q=0..11 (float4 loads).
// ---------------------------------------------------------------------------
__global__ __launch_bounds__(256) void sel_sparsemax_kernel(
    const float* __restrict__ sel_logits,
    unsigned* __restrict__ w_pack,
    int* __restrict__ w_cnt, float* __restrict__ w_c)
{
  const int row  = blockIdx.x * 4 + (threadIdx.x >> 6);
  const int lane = threadIdx.x & 63;
  const float* src = sel_logits + (size_t)row * F2;
  float4 z[12];
#pragma unroll
  for (int q = 0; q < 12; ++q)
    z[q] = *(const float4*)(src + q * 256 + lane * 4);

  float tau = -1e30f, taun = 0.f;
  int cprev = F2 + 1;
  for (int it = 0; it < 64; ++it) {
    float s = 0.f; int c = 0;
#pragma unroll
    for (int q = 0; q < 12; ++q) {
      const float* zq = (const float*)&z[q];
#pragma unroll
      for (int r = 0; r < 4; ++r) {
        const float v = zq[r];
        if (v > tau) { s += v; c++; }
      }
    }
    s = waveSum(s); c = waveSumI(c);
    taun = (s - 1.0f) / (float)c;
    if (c == cprev) break;
    cprev = c; tau = taun;
  }
  tau = taun;

  float chi = 0.f;
  float wv[24];
  int nnz = 0;
#pragma unroll
  for (int q = 0; q < 6; ++q) {
    const float* zlo = (const float*)&z[q];
    const float* zhi = (const float*)&z[q + 6];
#pragma unroll
    for (int r = 0; r < 4; ++r) {
      float lo = zlo[r] - tau; lo = lo > 0.f ? lo : 0.f;
      float hi = zhi[r] - tau; hi = hi > 0.f ? hi : 0.f;
      chi += hi;
      const float w = lo - hi;
      wv[q * 4 + r] = w;
      if (w != 0.f) nnz++;
    }
  }
  const float csum = waveSum(chi);
  if (lane == 0) w_c[row] = csum;

  int incl = nnz;
#pragma unroll
  for (int off = 1; off < 64; off <<= 1) {
    const int n = __shfl_up(incl, off, 64);
    if (lane >= off) incl += n;
  }
  const int tot = __shfl(incl, 63, 64);
  int pos = incl - nnz;
  unsigned* wrow = w_pack + (size_t)row * F1;
#pragma unroll
  for (int q = 0; q < 6; ++q) {
#pragma unroll
    for (int r = 0; r < 4; ++r) {
      const float w = wv[q * 4 + r];
      if (w != 0.f) {
        const unsigned idx = (unsigned)(q * 256 + lane * 4 + r);
        wrow[pos] = (idx << 16) | (unsigned)bf16_bits(w);
        pos++;
      }
    }
  }
  if (lane == 0) w_cnt[row] = tot;
  int npad = (tot + 255) & ~255;
  if (npad == 0) npad = 256;
  if (npad > F1) npad = F1;
  for (int i = tot + lane; i < npad; i += 64) wrow[i] = 0u;
}

// ---------------------------------------------------------------------------
// K2: f = sigmoid((x-thr)*exp(log_beta)) -> bf16 hi/lo pair [B][F1]
// ---------------------------------------------------------------------------
__global__ __launch_bounds__(256) void f_kernel(
    const float* __restrict__ x, const float* __restrict__ thr,
    const float* __restrict__ log_beta,
    __bf16* __restrict__ f_hi, __bf16* __restrict__ f_lo)
{
  const int b = blockIdx.x;
  const int d = threadIdx.x;
  const float xv = x[(size_t)b * D_ + d];
#pragma unroll
  for (int k = 0; k < KK_; ++k) {
    const float beta = __expf(log_beta[d * KK_ + k]);
    const float tt = (xv - thr[d * KK_ + k]) * beta;
    const float s = 1.0f / (1.0f + __expf(-tt));
    const __bf16 h = (__bf16)s;
    f_hi[(size_t)b * F1 + d * KK_ + k] = h;
    f_lo[(size_t)b * F1 + d * KK_ + k] = (__bf16)(s - (float)h);
  }
}

// ---------------------------------------------------------------------------
// K3: MFMA GEMM, part[sp][b][t], K = 4608 = [f_hi*w_hi | f_hi*w_lo | f_lo*w_hi]
// ---------------------------------------------------------------------------
__global__ __launch_bounds__(256) void gemm_mfma_kernel(
    const __bf16* __restrict__ f_hi, const __bf16* __restrict__ f_lo,
    const __bf16* __restrict__ w_hi, const __bf16* __restrict__ w_lo,
    float* __restrict__ part)
{
  __shared__ __bf16 As[2][64 * 64];
  __shared__ __bf16 Bs[2][64 * 64];
  const int bm = blockIdx.x * 64;
  const int bn = blockIdx.y * 64;
  const int sp = blockIdx.z;
  const int tid = threadIdx.x;
  const int wid = tid >> 6, lane = tid & 63;
  const int wr = wid >> 1, wc = wid & 1;

  const int srow = lane >> 3;
  const int skb8 = ((lane & 7) ^ srow) << 3;

  const int l15   = lane & 15;
  const int mask  = (lane & 7) << 4;
  const int khalf = (lane >> 4) << 4;
  int offA[2][2], offB[2][2];
#pragma unroll
  for (int m = 0; m < 2; ++m) {
    const int row = wr * 32 + m * 16 + l15;
#pragma unroll
    for (int s = 0; s < 2; ++s)
      offA[m][s] = row * 128 + (((s << 6) | khalf) ^ mask);
  }
#pragma unroll
  for (int n = 0; n < 2; ++n) {
    const int col = wc * 32 + n * 16 + l15;
#pragma unroll
    for (int s = 0; s < 2; ++s)
      offB[n][s] = col * 128 + (((s << 6) | khalf) ^ mask);
  }

  f32x4 acc[2][2] = {};

  auto stage = [&](int it, int buf) {
    const int k0  = sp * KSPL + it * BK;
    const int seg = k0 / KSEG;
    const int kl  = k0 - seg * KSEG;
    const __bf16* __restrict__ asrc = (seg < 2) ? f_hi : f_lo;
    const __bf16* __restrict__ bsrc = (seg == 1) ? w_lo : w_hi;
#pragma unroll
    for (int j = 0; j < 2; ++j) {
      const int q = wid * 2 + j;
      gload_lds16(asrc + (size_t)(bm + q * 8 + srow) * F1 + kl + skb8, &As[buf][q * 512]);
      gload_lds16(bsrc + (size_t)(bn + q * 8 + srow) * F1 + kl + skb8, &Bs[buf][q * 512]);
    }
  };

  stage(0, 0);
  __syncthreads();
  for (int it = 0; it < NIT; ++it) {
    const int cur = it & 1;
    if (it + 1 < NIT) stage(it + 1, cur ^ 1);
    const char* pa = (const char*)As[cur];
    const char* pb = (const char*)Bs[cur];
#pragma unroll
    for (int s = 0; s < 2; ++s) {
      const bf16x8 a0 = *(const bf16x8*)(pa + offA[0][s]);
      const bf16x8 a1 = *(const bf16x8*)(pa + offA[1][s]);
      const bf16x8 b0 = *(const bf16x8*)(pb + offB[0][s]);
      const bf16x8 b1 = *(const bf16x8*)(pb + offB[1][s]);
      acc[0][0] = __builtin_amdgcn_mfma_f32_16x16x32_bf16(a0, b0, acc[0][0], 0, 0, 0);
      acc[0][1] = __builtin_amdgcn_mfma_f32_16x16x32_bf16(a0, b1, acc[0][1], 0, 0, 0);
      acc[1][0] = __builtin_amdgcn_mfma_f32_16x16x32_bf16(a1, b0, acc[1][0], 0, 0, 0);
      acc[1][1] = __builtin_amdgcn_mfma_f32_16x16x32_bf16(a1, b1, acc[1][1], 0, 0, 0);
    }
    __syncthreads();
  }

  const int r0 = (lane >> 4) << 2;
  float* outp = part + (size_t)sp * B_ * T_;
#pragma unroll
  for (int m = 0; m < 2; ++m)
#pragma unroll
    for (int n = 0; n < 2; ++n)
#pragma unroll
      for (int r = 0; r < 4; ++r)
        outp[(size_t)(bm + wr * 32 + m * 16 + r0 + r) * T_ + (bn + wc * 32 + n * 16 + l15)] =
            acc[m][n][r];
}

// ---------------------------------------------------------------------------
// K4: fused split-K reduce + catt + per-row sparsemax over T=256 + compaction
// packed output: a_pack[b*T+i] = {bits(a_val), t}
// ---------------------------------------------------------------------------
__global__ __launch_bounds__(64) void att_sparsemax_kernel(
    const float* __restrict__ part, const float* __restrict__ catt,
    uint2* __restrict__ a_pack, int* __restrict__ a_cnt)
{
  const int b = blockIdx.x;
  const int lane = threadIdx.x;
  float z[4];
#pragma unroll
  for (int j = 0; j < 4; ++j) {
    const int t = lane + 64 * j;
    float s = catt[t];
#pragma unroll
    for (int sp = 0; sp < SPLITK; ++sp)
      s += part[((size_t)sp * B_ + b) * T_ + t];
    z[j] = s;
  }
  float tau = -1e30f, taun = 0.f;
  int cprev = T_ + 1;
  for (int it = 0; it < 40; ++it) {
    float s = 0.f; int c = 0;
#pragma unroll
    for (int j = 0; j < 4; ++j) if (z[j] > tau) { s += z[j]; c++; }
    s = waveSum(s); c = waveSumI(c);
    taun = (s - 1.0f) / (float)c;
    if (c == cprev) break;
    cprev = c; tau = taun;
  }
  tau = taun;
  float av[4]; int nnz = 0;
#pragma unroll
  for (int j = 0; j < 4; ++j) {
    float a = z[j] - tau; av[j] = a > 0.f ? a : 0.f;
    if (av[j] > 0.f) nnz++;
  }
  int incl = nnz;
#pragma unroll
  for (int off = 1; off < 64; off <<= 1) {
    const int n = __shfl_up(incl, off, 64);
    if (lane >= off) incl += n;
  }
  int pos = incl - nnz;
#pragma unroll
  for (int j = 0; j < 4; ++j) {
    if (av[j] > 0.f) {
      a_pack[(size_t)b * T_ + pos] =
          make_uint2(__float_as_uint(av[j]), (unsigned)(lane + 64 * j));
      pos++;
    }
  }
  if (lane == 63) a_cnt[b] = incl;
}

// ---------------------------------------------------------------------------
// K5: out[b,c] = sum over active t of a * sum_l prob_l * leaf[t,l,c]
// Phase 1: task-flattened (active-idx, depth) sparse dots -> p_sh[i][d]
//          4B records {u16 idx | bf16 val}, 4 chunks unconditional
// Phase 2: per active t, lane=leaf, product + leaf dot
// ---------------------------------------------------------------------------
__global__ __launch_bounds__(256) void final_kernel(
    const __bf16* __restrict__ f_hi, const __bf16* __restrict__ f_lo,
    const unsigned* __restrict__ w_pack,
    const int* __restrict__ w_cnt, const float* __restrict__ w_c,
    const uint2* __restrict__ a_pack, const int* __restrict__ a_cnt,
    const float* __restrict__ leaf, float* __restrict__ out)
{
  const int b = blockIdx.x;
  __shared__ float fl[F1];
  __shared__ float p_sh[T_][DEPTH_];
  __shared__ float oacc[4][C_];
  const int tid = threadIdx.x;
  const int wid = tid >> 6, lane = tid & 63;
  for (int i = tid; i < F1; i += 256)
    fl[i] = (float)f_hi[(size_t)b * F1 + i] + (float)f_lo[(size_t)b * F1 + i];
  __syncthreads();
  const int nact = a_cnt[b];
  const int ntask = nact * DEPTH_;

  for (int j = wid; j < ntask; j += 4) {
    const int i = j / 6;
    const int d = j - i * 6;
    const unsigned t = a_pack[(size_t)b * T_ + i].y;
    const int row = (int)t * DEPTH_ + d;
    const float wc = w_c[row];
    const int nk = (w_cnt[row] + 63) >> 6;
    const unsigned* wp = w_pack + (unsigned)(row * F1) + lane;
    const unsigned u0 = wp[0];
    const unsigned u1 = wp[64];
    const unsigned u2 = wp[128];
    const unsigned u3 = wp[192];
    float s = bf16_val(u0) * fl[u0 >> 16];
    s += bf16_val(u1) * fl[u1 >> 16];
    s += bf16_val(u2) * fl[u2 >> 16];
    s += bf16_val(u3) * fl[u3 >> 16];
    for (int k = 4; k < nk; ++k) {
      const unsigned u = wp[k * 64];
      s += bf16_val(u) * fl[u >> 16];
    }
    s = waveSum(s);
    if (lane == 0) {
      const float pv = wc + s;
      p_sh[i][d] = pv < 1e-6f ? 1e-6f : (pv > 1.0f - 1e-6f ? 1.0f - 1e-6f : pv);
    }
  }
  __syncthreads();

  float o[C_];
#pragma unroll
  for (int c = 0; c < C_; ++c) o[c] = 0.f;
  for (int i = wid; i < nact; i += 4) {
    const uint2 ap = a_pack[(size_t)b * T_ + i];
    float prob = __uint_as_float(ap.x);
#pragma unroll
    for (int d = 0; d < DEPTH_; ++d) {
      const float pv = p_sh[i][d];
      prob *= ((lane >> d) & 1) ? pv : (1.0f - pv);
    }
    const float* lf = leaf + ((size_t)ap.y * 64 + lane) * C_;
#pragma unroll
    for (int c = 0; c < C_; ++c) o[c] += prob * lf[c];
  }
#pragma unroll
  for (int c = 0; c < C_; ++c) o[c] = waveSum(o[c]);
  if (lane == 0) {
#pragma unroll
    for (int c = 0; c < C_; ++c) oacc[wid][c] = o[c];
  }
  __syncthreads();
  if (tid < C_)
    out[(size_t)b * C_ + tid] = oacc[0][tid] + oacc[1][tid] + oacc[2][tid] + oacc[3][tid];
}

// ---------------------------------------------------------------------------
extern "C" void kernel_launch(void* const* d_in, const int* in_sizes, int n_in,
                              void* d_out, int out_size, void* d_ws, size_t ws_size,
                              hipStream_t stream)
{
  const float* x        = (const float*)d_in[0];
  const float* thr      = (const float*)d_in[1];
  const float* log_beta = (const float*)d_in[2];
  const float* sel      = (const float*)d_in[3];
  const float* leaf     = (const float*)d_in[4];
  const float* att_W    = (const float*)d_in[5];
  const float* att_b    = (const float*)d_in[6];
  float* out = (float*)d_out;

  char* ws = (char*)d_ws;
  size_t off = 0;
  auto alloc = [&](size_t bytes) {
    char* p = ws + off;
    off = (off + bytes + 255) & ~(size_t)255;
    return p;
  };
  __bf16*         f_hi   = (__bf16*)alloc((size_t)B_ * F1 * 2);          // 12.6 MB
  __bf16*         f_lo   = (__bf16*)alloc((size_t)B_ * F1 * 2);          // 12.6 MB
  __bf16*         w_hi   = (__bf16*)alloc((size_t)T_ * F1 * 2);          //  0.8 MB
  __bf16*         w_lo   = (__bf16*)alloc((size_t)T_ * F1 * 2);          //  0.8 MB
  float*          catt   = (float*)alloc((size_t)T_ * 4);
  float*          pc     = (float*)alloc((size_t)NFB * T_ * 4);
  unsigned*       w_pack = (unsigned*)alloc((size_t)NROW * F1 * 4);      //  9.4 MB
  int*            w_cnt  = (int*)alloc((size_t)NROW * 4);
  float*          w_c    = (float*)alloc((size_t)NROW * 4);
  float*          part   = (float*)alloc((size_t)SPLITK * B_ * T_ * 4);  // 16.8 MB
  uint2*          a_pack = (uint2*)alloc((size_t)B_ * T_ * 8);           //  8.4 MB
  int*            a_cnt  = (int*)alloc((size_t)B_ * 4);
  (void)ws_size; (void)in_sizes; (void)n_in; (void)out_size;             // ~62 MB total

  hipLaunchKernelGGL(prep_att_kernel,      dim3(NFB, T_ / 64),        dim3(256), 0, stream, att_W, w_hi, w_lo, pc);
  hipLaunchKernelGGL(catt_kernel,          dim3(1),                   dim3(256), 0, stream, pc, att_b, catt);
  hipLaunchKernelGGL(sel_sparsemax_kernel, dim3(NROW / 4),            dim3(256), 0, stream, sel, w_pack, w_cnt, w_c);
  hipLaunchKernelGGL(f_kernel,             dim3(B_),                  dim3(256), 0, stream, x, thr, log_beta, f_hi, f_lo);
  hipLaunchKernelGGL(gemm_mfma_kernel,     dim3(B_ / 64, T_ / 64, SPLITK), dim3(256), 0, stream, f_hi, f_lo, w_hi, w_lo, part);
  hipLaunchKernelGGL(att_sparsemax_kernel, dim3(B_),                  dim3(64),  0, stream, part, catt, a_pack, a_cnt);
  hipLaunchKernelGGL(final_kernel,         dim3(B_),                  dim3(256), 0, stream, f_hi, f_lo, w_pack, w_cnt, w_c, a_pack, a_cnt, leaf, out);
}

// Round 6
// 98.215 us; speedup vs baseline: 1.3636x; 1.0596x over previous
//
#include <hip/hip_runtime.h>
#include <cstdint>

#define B_     4096
#define D_     256
#define KK_    6
#define T_     256
#define DEPTH_ 6
#define C_     8
#define F1     1536   // D*K
#define F2     3072   // 2*F1
#define NROW   1536   // T*DEPTH
#define SPLITK 4
#define KSPL   384    // F1 / SPLITK
#define BK     64
#define NIT    (KSPL / BK)   // 6
#define NFB    24     // F1/64 blocks for prep_att
#define NTASKMAX (T_ * DEPTH_)

using bf16x8 = __attribute__((ext_vector_type(8))) __bf16;
using f32x4  = __attribute__((ext_vector_type(4))) float;

__device__ inline float waveSum(float v) {
#pragma unroll
  for (int m = 32; m; m >>= 1) v += __shfl_xor(v, m, 64);
  return v;
}
__device__ inline int waveSumI(int v) {
#pragma unroll
  for (int m = 32; m; m >>= 1) v += __shfl_xor(v, m, 64);
  return v;
}

__device__ inline unsigned short bf16_bits(float v) {   // round-to-nearest-even
  const unsigned u = __float_as_uint(v);
  return (unsigned short)((u + 0x7FFFu + ((u >> 16) & 1u)) >> 16);
}
__device__ inline float bf16_val(unsigned rec) {        // low 16 bits -> f32
  return __uint_as_float(rec << 16);
}

__device__ __forceinline__ void gload_lds16(const void* g, void* l) {
  __builtin_amdgcn_global_load_lds(
      (const __attribute__((address_space(1))) unsigned int*)g,
      (__attribute__((address_space(3))) unsigned int*)l, 16, 0, 0);
}

// ---------------------------------------------------------------------------
// K0a: tile-transpose att_W -> w_hi bf16 [T][F1]; partial catt col sums
// w[t][f] = W[f][t] - W[f+F1][t];  pc[fb][t] = sum_{f in blk} W[f+F1][t]
// ---------------------------------------------------------------------------
__global__ __launch_bounds__(256) void prep_att_kernel(
    const float* __restrict__ att_W,
    __bf16* __restrict__ w_hi,
    float* __restrict__ pc)
{
  const int fblk = blockIdx.x * 64;   // over F1
  const int tblk = blockIdx.y * 64;   // over T
  __shared__ float Wl[64][65], Wh[64][65];
  const int tt = threadIdx.x & 63;
  const int f4 = threadIdx.x >> 6;
#pragma unroll
  for (int r = 0; r < 16; ++r) {
    const int f = r * 4 + f4;
    Wl[f][tt] = att_W[(size_t)(fblk + f) * T_ + tblk + tt];
    Wh[f][tt] = att_W[(size_t)(fblk + f + F1) * T_ + tblk + tt];
  }
  __syncthreads();
  const int t  = threadIdx.x >> 2;
  const int fq = threadIdx.x & 3;
#pragma unroll
  for (int pass = 0; pass < 4; ++pass) {
    const int f0 = pass * 16 + fq * 4;
    alignas(8) __bf16 hv[4];
#pragma unroll
    for (int e = 0; e < 4; ++e)
      hv[e] = (__bf16)(Wl[f0 + e][t] - Wh[f0 + e][t]);
    *(uint2*)&w_hi[(size_t)(tblk + t) * F1 + fblk + f0] = *(const uint2*)hv;
  }
  if (threadIdx.x < 64) {
    float s = 0.f;
#pragma unroll
    for (int f = 0; f < 64; ++f) s += Wh[f][threadIdx.x];
    pc[(size_t)blockIdx.x * T_ + tblk + threadIdx.x] = s;
  }
}

__global__ __launch_bounds__(256) void catt_kernel(
    const float* __restrict__ pc, const float* __restrict__ att_b,
    float* __restrict__ catt)
{
  const int t = threadIdx.x;
  float s = att_b[t];
  for (int i = 0; i < NFB; ++i) s += pc[(size_t)i * T_ + t];
  catt[t] = s;
}

// ---------------------------------------------------------------------------
// K1: per-row sparsemax of sel_logits, 1 wave per row, all-register Michelot.
// Output: packed records {u16 idx | bf16 val} + const c; rows zero-padded to
// a multiple of 256 records.
// ---------------------------------------------------------------------------
__global__ __launch_bounds__(256) void sel_sparsemax_kernel(
    const float* __restrict__ sel_logits,
    unsigned* __restrict__ w_pack,
    int* __restrict__ w_cnt, float* __restrict__ w_c)
{
  const int row  = blockIdx.x * 4 + (threadIdx.x >> 6);
  const int lane = threadIdx.x & 63;
  const float* src = sel_logits + (size_t)row * F2;
  float4 z[12];
#pragma unroll
  for (int q = 0; q < 12; ++q)
    z[q] = *(const float4*)(src + q * 256 + lane * 4);

  float tau = -1e30f, taun = 0.f;
  int cprev = F2 + 1;
  for (int it = 0; it < 64; ++it) {
    float s = 0.f; int c = 0;
#pragma unroll
    for (int q = 0; q < 12; ++q) {
      const float* zq = (const float*)&z[q];
#pragma unroll
      for (int r = 0; r < 4; ++r) {
        const float v = zq[r];
        if (v > tau) { s += v; c++; }
      }
    }
    s = waveSum(s); c = waveSumI(c);
    taun = (s - 1.0f) / (float)c;
    if (c == cprev) break;
    cprev = c; tau = taun;
  }
  tau = taun;

  float chi = 0.f;
  float wv[24];
  int nnz = 0;
#pragma unroll
  for (int q = 0; q < 6; ++q) {
    const float* zlo = (const float*)&z[q];
    const float* zhi = (const float*)&z[q + 6];
#pragma unroll
    for (int r = 0; r < 4; ++r) {
      float lo = zlo[r] - tau; lo = lo > 0.f ? lo : 0.f;
      float hi = zhi[r] - tau; hi = hi > 0.f ? hi : 0.f;
      chi += hi;
      const float w = lo - hi;
      wv[q * 4 + r] = w;
      if (w != 0.f) nnz++;
    }
  }
  const float csum = waveSum(chi);
  if (lane == 0) w_c[row] = csum;

  int incl = nnz;
#pragma unroll
  for (int off = 1; off < 64; off <<= 1) {
    const int n = __shfl_up(incl, off, 64);
    if (lane >= off) incl += n;
  }
  const int tot = __shfl(incl, 63, 64);
  int pos = incl - nnz;
  unsigned* wrow = w_pack + (size_t)row * F1;
#pragma unroll
  for (int q = 0; q < 6; ++q) {
#pragma unroll
    for (int r = 0; r < 4; ++r) {
      const float w = wv[q * 4 + r];
      if (w != 0.f) {
        const unsigned idx = (unsigned)(q * 256 + lane * 4 + r);
        wrow[pos] = (idx << 16) | (unsigned)bf16_bits(w);
        pos++;
      }
    }
  }
  if (lane == 0) w_cnt[row] = tot;
  int npad = (tot + 255) & ~255;
  if (npad == 0) npad = 256;
  if (npad > F1) npad = F1;
  for (int i = tot + lane; i < npad; i += 64) wrow[i] = 0u;
}

// ---------------------------------------------------------------------------
// K2: f = sigmoid((x-thr)*exp(log_beta)) -> bf16 hi/lo pair [B][F1]
// ---------------------------------------------------------------------------
__global__ __launch_bounds__(256) void f_kernel(
    const float* __restrict__ x, const float* __restrict__ thr,
    const float* __restrict__ log_beta,
    __bf16* __restrict__ f_hi, __bf16* __restrict__ f_lo)
{
  const int b = blockIdx.x;
  const int d = threadIdx.x;
  const float xv = x[(size_t)b * D_ + d];
  alignas(4) __bf16 hv[6], lv[6];
#pragma unroll
  for (int k = 0; k < KK_; ++k) {
    const float beta = __expf(log_beta[d * KK_ + k]);
    const float tt = (xv - thr[d * KK_ + k]) * beta;
    const float s = 1.0f / (1.0f + __expf(-tt));
    const __bf16 h = (__bf16)s;
    hv[k] = h;
    lv[k] = (__bf16)(s - (float)h);
  }
  const size_t base = (size_t)b * F1 + d * KK_;
  const unsigned* hp = (const unsigned*)hv;
  const unsigned* lp = (const unsigned*)lv;
  unsigned* dh = (unsigned*)&f_hi[base];
  unsigned* dl = (unsigned*)&f_lo[base];
  dh[0] = hp[0]; dh[1] = hp[1]; dh[2] = hp[2];
  dl[0] = lp[0]; dl[1] = lp[1]; dl[2] = lp[2];
}

// ---------------------------------------------------------------------------
// K3: MFMA GEMM, part[sp][b][t] over K-slice of F1 (bf16 f_hi x w_hi)
// ---------------------------------------------------------------------------
__global__ __launch_bounds__(256) void gemm_mfma_kernel(
    const __bf16* __restrict__ f_hi, const __bf16* __restrict__ w_hi,
    float* __restrict__ part)
{
  __shared__ __bf16 As[2][64 * 64];
  __shared__ __bf16 Bs[2][64 * 64];
  const int bm = blockIdx.x * 64;
  const int bn = blockIdx.y * 64;
  const int sp = blockIdx.z;
  const int tid = threadIdx.x;
  const int wid = tid >> 6, lane = tid & 63;
  const int wr = wid >> 1, wc = wid & 1;

  const int srow = lane >> 3;
  const int skb8 = ((lane & 7) ^ srow) << 3;

  const int l15   = lane & 15;
  const int mask  = (lane & 7) << 4;
  const int khalf = (lane >> 4) << 4;
  int offA[2][2], offB[2][2];
#pragma unroll
  for (int m = 0; m < 2; ++m) {
    const int row = wr * 32 + m * 16 + l15;
#pragma unroll
    for (int s = 0; s < 2; ++s)
      offA[m][s] = row * 128 + (((s << 6) | khalf) ^ mask);
  }
#pragma unroll
  for (int n = 0; n < 2; ++n) {
    const int col = wc * 32 + n * 16 + l15;
#pragma unroll
    for (int s = 0; s < 2; ++s)
      offB[n][s] = col * 128 + (((s << 6) | khalf) ^ mask);
  }

  f32x4 acc[2][2] = {};

  auto stage = [&](int it, int buf) {
    const int kl = sp * KSPL + it * BK;
#pragma unroll
    for (int j = 0; j < 2; ++j) {
      const int q = wid * 2 + j;
      gload_lds16(f_hi + (size_t)(bm + q * 8 + srow) * F1 + kl + skb8, &As[buf][q * 512]);
      gload_lds16(w_hi + (size_t)(bn + q * 8 + srow) * F1 + kl + skb8, &Bs[buf][q * 512]);
    }
  };

  stage(0, 0);
  __syncthreads();
  for (int it = 0; it < NIT; ++it) {
    const int cur = it & 1;
    if (it + 1 < NIT) stage(it + 1, cur ^ 1);
    const char* pa = (const char*)As[cur];
    const char* pb = (const char*)Bs[cur];
#pragma unroll
    for (int s = 0; s < 2; ++s) {
      const bf16x8 a0 = *(const bf16x8*)(pa + offA[0][s]);
      const bf16x8 a1 = *(const bf16x8*)(pa + offA[1][s]);
      const bf16x8 b0 = *(const bf16x8*)(pb + offB[0][s]);
      const bf16x8 b1 = *(const bf16x8*)(pb + offB[1][s]);
      acc[0][0] = __builtin_amdgcn_mfma_f32_16x16x32_bf16(a0, b0, acc[0][0], 0, 0, 0);
      acc[0][1] = __builtin_amdgcn_mfma_f32_16x16x32_bf16(a0, b1, acc[0][1], 0, 0, 0);
      acc[1][0] = __builtin_amdgcn_mfma_f32_16x16x32_bf16(a1, b0, acc[1][0], 0, 0, 0);
      acc[1][1] = __builtin_amdgcn_mfma_f32_16x16x32_bf16(a1, b1, acc[1][1], 0, 0, 0);
    }
    __syncthreads();
  }

  const int r0 = (lane >> 4) << 2;
  float* outp = part + (size_t)sp * B_ * T_;
#pragma unroll
  for (int m = 0; m < 2; ++m)
#pragma unroll
    for (int n = 0; n < 2; ++n)
#pragma unroll
      for (int r = 0; r < 4; ++r)
        outp[(size_t)(bm + wr * 32 + m * 16 + r0 + r) * T_ + (bn + wc * 32 + n * 16 + l15)] =
            acc[m][n][r];
}

// ---------------------------------------------------------------------------
// K4: fused split-K reduce + catt + per-row sparsemax over T=256 + compaction
// packed output: a_pack[b*T+i] = {bits(a_val), t}
// ---------------------------------------------------------------------------
__global__ __launch_bounds__(64) void att_sparsemax_kernel(
    const float* __restrict__ part, const float* __restrict__ catt,
    uint2* __restrict__ a_pack, int* __restrict__ a_cnt)
{
  const int b = blockIdx.x;
  const int lane = threadIdx.x;
  float z[4];
#pragma unroll
  for (int j = 0; j < 4; ++j) {
    const int t = lane + 64 * j;
    float s = catt[t];
#pragma unroll
    for (int sp = 0; sp < SPLITK; ++sp)
      s += part[((size_t)sp * B_ + b) * T_ + t];
    z[j] = s;
  }
  float tau = -1e30f, taun = 0.f;
  int cprev = T_ + 1;
  for (int it = 0; it < 40; ++it) {
    float s = 0.f; int c = 0;
#pragma unroll
    for (int j = 0; j < 4; ++j) if (z[j] > tau) { s += z[j]; c++; }
    s = waveSum(s); c = waveSumI(c);
    taun = (s - 1.0f) / (float)c;
    if (c == cprev) break;
    cprev = c; tau = taun;
  }
  tau = taun;
  float av[4]; int nnz = 0;
#pragma unroll
  for (int j = 0; j < 4; ++j) {
    float a = z[j] - tau; av[j] = a > 0.f ? a : 0.f;
    if (av[j] > 0.f) nnz++;
  }
  int incl = nnz;
#pragma unroll
  for (int off = 1; off < 64; off <<= 1) {
    const int n = __shfl_up(incl, off, 64);
    if (lane >= off) incl += n;
  }
  int pos = incl - nnz;
#pragma unroll
  for (int j = 0; j < 4; ++j) {
    if (av[j] > 0.f) {
      a_pack[(size_t)b * T_ + pos] =
          make_uint2(__float_as_uint(av[j]), (unsigned)(lane + 64 * j));
      pos++;
    }
  }
  if (lane == 63) a_cnt[b] = incl;
}

// ---------------------------------------------------------------------------
// K5: out[b,c] = sum over active t of a * sum_l prob_l * leaf[t,l,c]
// Prologue: all task metadata (row, nk, w_c) resolved in parallel into LDS.
// Phase 1: task loop, chunk loads software-pipelined 1 task ahead.
// Phase 2: per active t, lane=leaf, product + leaf dot.
// ---------------------------------------------------------------------------
__global__ __launch_bounds__(256) void final_kernel(
    const __bf16* __restrict__ f_hi, const __bf16* __restrict__ f_lo,
    const unsigned* __restrict__ w_pack,
    const int* __restrict__ w_cnt, const float* __restrict__ w_c,
    const uint2* __restrict__ a_pack, const int* __restrict__ a_cnt,
    const float* __restrict__ leaf, float* __restrict__ out)
{
  const int b = blockIdx.x;
  __shared__ float fl[F1];
  __shared__ float p_sh[T_][DEPTH_];
  __shared__ unsigned short meta_rn[NTASKMAX];   // (row<<5)|nk
  __shared__ float meta_wc[NTASKMAX];
  __shared__ uint2 ash[T_];
  __shared__ float oacc[4][C_];
  const int tid = threadIdx.x;
  const int wid = tid >> 6, lane = tid & 63;

  const int nact = a_cnt[b];
  const int ntask = nact * DEPTH_;
  for (int i = tid; i < nact; i += 256) ash[i] = a_pack[(size_t)b * T_ + i];
  for (int i = tid; i < F1; i += 256)
    fl[i] = (float)f_hi[(size_t)b * F1 + i] + (float)f_lo[(size_t)b * F1 + i];
  __syncthreads();

  // metadata: all dependent loads issued concurrently across 256 threads
  for (int j = tid; j < ntask; j += 256) {
    const int i = j / 6;
    const int d = j - i * 6;
    const int row = (int)ash[i].y * DEPTH_ + d;
    int nk = (w_cnt[row] + 63) >> 6;
    meta_rn[j] = (unsigned short)((row << 5) | nk);
    meta_wc[j] = w_c[row];
  }
  __syncthreads();

  // Phase 1: wave-per-task, 1-deep prefetch pipeline
  float* p_lin = &p_sh[0][0];
  int j = wid;
  unsigned cur0 = 0, cur1 = 0, cur2 = 0, cur3 = 0, currow = 0, curnk = 0;
  if (j < ntask) {
    const unsigned rn = meta_rn[j];
    currow = rn >> 5; curnk = rn & 31u;
    const unsigned* wp = w_pack + currow * F1 + lane;
    cur0 = wp[0]; cur1 = wp[64]; cur2 = wp[128]; cur3 = wp[192];
  }
  while (j < ntask) {
    const int jn = j + 4;
    unsigned n0 = 0, n1 = 0, n2 = 0, n3 = 0, nrow = 0, nnk = 0;
    if (jn < ntask) {
      const unsigned rn = meta_rn[jn];
      nrow = rn >> 5; nnk = rn & 31u;
      const unsigned* wp = w_pack + nrow * F1 + lane;
      n0 = wp[0]; n1 = wp[64]; n2 = wp[128]; n3 = wp[192];
    }
    float s = bf16_val(cur0) * fl[cur0 >> 16];
    s += bf16_val(cur1) * fl[cur1 >> 16];
    s += bf16_val(cur2) * fl[cur2 >> 16];
    s += bf16_val(cur3) * fl[cur3 >> 16];
    if (curnk > 4) {
      const unsigned* wp = w_pack + currow * F1 + lane;
      for (unsigned k = 4; k < curnk; ++k) {
        const unsigned u = wp[k * 64];
        s += bf16_val(u) * fl[u >> 16];
      }
    }
    s = waveSum(s);
    if (lane == 0) {
      const float pv = meta_wc[j] + s;
      p_lin[j] = pv < 1e-6f ? 1e-6f : (pv > 1.0f - 1e-6f ? 1.0f - 1e-6f : pv);
    }
    j = jn;
    cur0 = n0; cur1 = n1; cur2 = n2; cur3 = n3; currow = nrow; curnk = nnk;
  }
  __syncthreads();

  // Phase 2: lane = leaf index
  float o[C_];
#pragma unroll
  for (int c = 0; c < C_; ++c) o[c] = 0.f;
  for (int i = wid; i < nact; i += 4) {
    const uint2 ap = ash[i];
    float prob = __uint_as_float(ap.x);
#pragma unroll
    for (int d = 0; d < DEPTH_; ++d) {
      const float pv = p_sh[i][d];
      prob *= ((lane >> d) & 1) ? pv : (1.0f - pv);
    }
    const float* lf = leaf + ((size_t)ap.y * 64 + lane) * C_;
#pragma unroll
    for (int c = 0; c < C_; ++c) o[c] += prob * lf[c];
  }
#pragma unroll
  for (int c = 0; c < C_; ++c) o[c] = waveSum(o[c]);
  if (lane == 0) {
#pragma unroll
    for (int c = 0; c < C_; ++c) oacc[wid][c] = o[c];
  }
  __syncthreads();
  if (tid < C_)
    out[(size_t)b * C_ + tid] = oacc[0][tid] + oacc[1][tid] + oacc[2][tid] + oacc[3][tid];
}

// ---------------------------------------------------------------------------
extern "C" void kernel_launch(void* const* d_in, const int* in_sizes, int n_in,
                              void* d_out, int out_size, void* d_ws, size_t ws_size,
                              hipStream_t stream)
{
  const float* x        = (const float*)d_in[0];
  const float* thr      = (const float*)d_in[1];
  const float* log_beta = (const float*)d_in[2];
  const float* sel      = (const float*)d_in[3];
  const float* leaf     = (const float*)d_in[4];
  const float* att_W    = (const float*)d_in[5];
  const float* att_b    = (const float*)d_in[6];
  float* out = (float*)d_out;

  char* ws = (char*)d_ws;
  size_t off = 0;
  auto alloc = [&](size_t bytes) {
    char* p = ws + off;
    off = (off + bytes + 255) & ~(size_t)255;
    return p;
  };
  __bf16*         f_hi   = (__bf16*)alloc((size_t)B_ * F1 * 2);          // 12.6 MB
  __bf16*         f_lo   = (__bf16*)alloc((size_t)B_ * F1 * 2);          // 12.6 MB
  __bf16*         w_hi   = (__bf16*)alloc((size_t)T_ * F1 * 2);          //  0.8 MB
  float*          catt   = (float*)alloc((size_t)T_ * 4);
  float*          pc     = (float*)alloc((size_t)NFB * T_ * 4);
  unsigned*       w_pack = (unsigned*)alloc((size_t)NROW * F1 * 4);      //  9.4 MB
  int*            w_cnt  = (int*)alloc((size_t)NROW * 4);
  float*          w_c    = (float*)alloc((size_t)NROW * 4);
  float*          part   = (float*)alloc((size_t)SPLITK * B_ * T_ * 4);  // 16.8 MB
  uint2*          a_pack = (uint2*)alloc((size_t)B_ * T_ * 8);           //  8.4 MB
  int*            a_cnt  = (int*)alloc((size_t)B_ * 4);
  (void)ws_size; (void)in_sizes; (void)n_in; (void)out_size;             // ~61 MB total

  hipLaunchKernelGGL(prep_att_kernel,      dim3(NFB, T_ / 64),        dim3(256), 0, stream, att_W, w_hi, pc);
  hipLaunchKernelGGL(catt_kernel,          dim3(1),                   dim3(256), 0, stream, pc, att_b, catt);
  hipLaunchKernelGGL(sel_sparsemax_kernel, dim3(NROW / 4),            dim3(256), 0, stream, sel, w_pack, w_cnt, w_c);
  hipLaunchKernelGGL(f_kernel,             dim3(B_),                  dim3(256), 0, stream, x, thr, log_beta, f_hi, f_lo);
  hipLaunchKernelGGL(gemm_mfma_kernel,     dim3(B_ / 64, T_ / 64, SPLITK), dim3(256), 0, stream, f_hi, w_hi, part);
  hipLaunchKernelGGL(att_sparsemax_kernel, dim3(B_),                  dim3(64),  0, stream, part, catt, a_pack, a_cnt);
  hipLaunchKernelGGL(final_kernel,         dim3(B_),                  dim3(256), 0, stream, f_hi, f_lo, w_pack, w_cnt, w_c, a_pack, a_cnt, leaf, out);
}